// Round 8
// baseline (470.647 us; speedup 1.0000x reference)
//
#include <hip/hip_runtime.h>
#include <hip/hip_bf16.h>
#include <cmath>

#define N_TOK 32768
#define DIM   256
#define NEXP  8
#define HID   1024
#define BM    64
#define BH    64
#define MAXT  512   // MAXT*BM == N_TOK: covers worst-case expert load

typedef short bf16x8 __attribute__((ext_vector_type(8)));
typedef float f32x4  __attribute__((ext_vector_type(4)));

__device__ __forceinline__ ushort f2bf(float f) {
  unsigned u = __builtin_bit_cast(unsigned, f);
  u += 0x7fffu + ((u >> 16) & 1u);   // RNE; inputs are well-behaved (no NaN/Inf)
  return (ushort)(u >> 16);
}

// lh swizzle (128B rows): 16B-slot XOR, max 112 < 128 -> bijective in-row.
__device__ __forceinline__ int lh_slot(int row) {
  return ((row ^ (row >> 3)) & 7) << 4;
}
// lx swizzle (512B rows): round-1-proven (r&7)<<4, max 112 < 512, bijective.
__device__ __forceinline__ int lx_slot(int row) {
  return (row & 7) << 4;
}

// ---------- transpose + cast: src[E][R][C] f32 -> dst[E][C][R] bf16 ----------
__global__ __launch_bounds__(256) void k_transpose_cast(
    const float* __restrict__ src, ushort* __restrict__ dst, int R, int C)
{
  __shared__ float tile[32][33];
  int e = blockIdx.z, rb = blockIdx.y, cb = blockIdx.x;
  int tx = threadIdx.x, ty = threadIdx.y;           // 32 x 8
  const float* s = src + (size_t)e * R * C;
  ushort* d = dst + (size_t)e * R * C;
#pragma unroll
  for (int j = 0; j < 4; ++j)
    tile[ty + 8*j][tx] = s[(size_t)(rb*32 + ty + 8*j) * C + cb*32 + tx];
  __syncthreads();
#pragma unroll
  for (int j = 0; j < 4; ++j)
    d[(size_t)(cb*32 + ty + 8*j) * R + rb*32 + tx] = f2bf(tile[tx][ty + 8*j]);
}

// ---------- router: fp64 logits, softmax, top-2, bucket scatter ----------
__global__ __launch_bounds__(256) void k_router(
    const float* __restrict__ x, const float* __restrict__ grad,
    const float* __restrict__ Wr, const float* __restrict__ br,
    float* __restrict__ probs_out,
    int* __restrict__ cnt, int* __restrict__ tok, float* __restrict__ wgt)
{
  __shared__ float xt[256][33];
  __shared__ float wrs[257*8];
  __shared__ float brs[8];
  __shared__ int lcnt[8], lbase[8];
  int tid = threadIdx.x;
  int n = blockIdx.x * 256 + tid;

  for (int i = tid; i < 257*8; i += 256) wrs[i] = Wr[i];
  if (tid < 8) { brs[tid] = br[tid]; lcnt[tid] = 0; }

  double acc[8] = {0,0,0,0,0,0,0,0};
  for (int ch = 0; ch < 8; ++ch) {
    __syncthreads();
    for (int f = tid; f < 2048; f += 256) {          // 256 rows x 32 cols, float4
      int r = f >> 3, c0 = (f & 7) * 4;
      float4 v = *(const float4*)(x + (size_t)(blockIdx.x*256 + r)*DIM + ch*32 + c0);
      xt[r][c0] = v.x; xt[r][c0+1] = v.y; xt[r][c0+2] = v.z; xt[r][c0+3] = v.w;
    }
    __syncthreads();
#pragma unroll 4
    for (int c = 0; c < 32; ++c) {
      double xv = (double)xt[tid][c];
      const float* wr = &wrs[(ch*32 + c)*8];
#pragma unroll
      for (int e = 0; e < 8; ++e) acc[e] += xv * (double)wr[e];
    }
  }
  double g = (double)grad[n];
  double lg[8];
#pragma unroll
  for (int e = 0; e < 8; ++e) lg[e] = acc[e] + g*(double)wrs[256*8+e] + (double)brs[e];
  double m = lg[0];
#pragma unroll
  for (int e = 1; e < 8; ++e) m = lg[e] > m ? lg[e] : m;
  double p[8], s = 0.0;
#pragma unroll
  for (int e = 0; e < 8; ++e) { p[e] = exp(lg[e]-m); s += p[e]; }
  double inv = 1.0/s;
#pragma unroll
  for (int e = 0; e < 8; ++e) probs_out[(size_t)n*8 + e] = (float)(p[e]*inv);

  // top-2, ties -> lower index (matches lax.top_k)
  int i0 = 0;
#pragma unroll
  for (int e = 1; e < 8; ++e) if (lg[e] > lg[i0]) i0 = e;
  int i1 = (i0 == 0) ? 1 : 0;
#pragma unroll
  for (int e = 0; e < 8; ++e) if (e != i0 && lg[e] > lg[i1]) i1 = e;
  float w0 = (float)(p[i0]*inv), w1 = (float)(p[i1]*inv);

  int p0 = atomicAdd(&lcnt[i0], 1);
  int p1 = atomicAdd(&lcnt[i1], 1);
  __syncthreads();
  if (tid < 8) lbase[tid] = atomicAdd(&cnt[tid], lcnt[tid]);
  __syncthreads();
  tok[i0*N_TOK + lbase[i0] + p0] = n;  wgt[i0*N_TOK + lbase[i0] + p0] = w0;
  tok[i1*N_TOK + lbase[i1] + p1] = n;  wgt[i1*N_TOK + lbase[i1] + p1] = w1;
}

// ---------- fused gathered expert MLP: out += w * (gelu(x@W1+b1)@W2 + b2) ----------
// (256,2): VGPR cap 256/wave; tighter caps spilled to scratch (FETCH 530-938 MB).
// e = bid&7: XCD x runs only expert x -> weights L2-resident (FETCH 69->40 MB, r7).
// NEW (r8): chunk schedule staggered per block. Without stagger, all 32 CUs of
// an XCD read the SAME 96 KB of W lines in lockstep -> L2 bank queueing theory.
__global__ __launch_bounds__(256, 2) void k_moe(
    const float* __restrict__ x,
    const ushort* __restrict__ w1t,   // [E][H][D] bf16 (transposed)
    const ushort* __restrict__ w2t,   // [E][D][H] bf16 (transposed)
    const float* __restrict__ bias1,  // [E][H]
    const float* __restrict__ bias2,  // [E][D]
    const int* __restrict__ cnt, const int* __restrict__ tok,
    const float* __restrict__ wgt,
    float* __restrict__ out)
{
  int e    = blockIdx.x & 7;
  int tile = blockIdx.x >> 3;
  int c = cnt[e];
  int row0 = tile * BM;
  if (row0 >= c) return;
  int rows = min(BM, c - row0);
  int phase = tile & 15;              // stagger: concurrent blocks hit different W chunks

  __shared__ ushort lx[BM * DIM];     // 32 KB, swizzled rows
  __shared__ ushort lh[2][BM * BH];   // 16 KB double-buffered h tile

  int tid  = threadIdx.x;
  int lane = tid & 63;
  int wid  = tid >> 6;
  const int l15 = lane & 15;
  const int lk8 = (lane >> 4) * 8;
  const int lr4 = (lane >> 4) * 4;
  const int wr = wid >> 1, wc = wid & 1;   // 2x2 wave grid for GEMM1

  const int*   etok = tok + e * N_TOK + row0;
  const float* ewgt = wgt + e * N_TOK + row0;

  // ---- stage x rows -> bf16 swizzled LDS (coalesced) ----
  for (int f = tid; f < BM * (DIM/4); f += 256) {
    int r = f >> 6, c4 = f & 63;
    int t = etok[min(r, rows - 1)];
    float4 v = *(const float4*)(x + (size_t)t * DIM + c4 * 4);
    ushort4 b;
    b.x = f2bf(v.x); b.y = f2bf(v.y); b.z = f2bf(v.z); b.w = f2bf(v.w);
    *(ushort4*)((char*)lx + r * 512 + ((c4 * 8) ^ lx_slot(r))) = b;
  }
  __syncthreads();

  // ---- hoist A-fragments to registers once ----
  bf16x8 areg[2][8];
#pragma unroll
  for (int fr = 0; fr < 2; ++fr) {
    int row = wr*32 + fr*16 + l15;
#pragma unroll
    for (int k = 0; k < 8; ++k)
      areg[fr][k] = *(const bf16x8*)((const char*)lx + row*512
                      + (((k*32 + lk8)*2) ^ lx_slot(row)));
  }

  f32x4 accY[4][4];
#pragma unroll
  for (int i = 0; i < 4; ++i)
#pragma unroll
    for (int j = 0; j < 4; ++j) accY[i][j] = (f32x4){0.f,0.f,0.f,0.f};

  const ushort* W1e = w1t + (size_t)e * HID * DIM;
  const ushort* W2e = w2t + (size_t)e * DIM * HID;

  int sl2[4];
#pragma unroll
  for (int fr = 0; fr < 4; ++fr) sl2[fr] = lh_slot(fr*16 + l15);

  for (int cc = 0; cc < HID / BH; ++cc) {
    int chunk = (cc + phase) & 15;    // staggered chunk order (sum reorder only)
    int h0 = chunk * BH;

    // prefetch this chunk's W2 B-fragments
    bf16x8 bw[2][4];
#pragma unroll
    for (int k2 = 0; k2 < 2; ++k2)
#pragma unroll
      for (int fc = 0; fc < 4; ++fc)
        bw[k2][fc] = *(const bf16x8*)(W2e + (size_t)(wid*64 + fc*16 + l15) * HID
                                      + h0 + k2*32 + lk8);

    f32x4 accH[2][2];
#pragma unroll
    for (int i = 0; i < 2; ++i)
#pragma unroll
      for (int j = 0; j < 2; ++j) accH[i][j] = (f32x4){0.f,0.f,0.f,0.f};

    // GEMM1: h[64x64] = x[64x256] @ W1[256x64], A from registers
#pragma unroll
    for (int k = 0; k < 8; ++k) {
      bf16x8 b0 = *(const bf16x8*)(W1e + (size_t)(h0 + wc*32 +      l15) * DIM + k*32 + lk8);
      bf16x8 b1 = *(const bf16x8*)(W1e + (size_t)(h0 + wc*32 + 16 + l15) * DIM + k*32 + lk8);
      accH[0][0] = __builtin_amdgcn_mfma_f32_16x16x32_bf16(areg[0][k], b0, accH[0][0], 0, 0, 0);
      accH[1][0] = __builtin_amdgcn_mfma_f32_16x16x32_bf16(areg[1][k], b0, accH[1][0], 0, 0, 0);
      accH[0][1] = __builtin_amdgcn_mfma_f32_16x16x32_bf16(areg[0][k], b1, accH[0][1], 0, 0, 0);
      accH[1][1] = __builtin_amdgcn_mfma_f32_16x16x32_bf16(areg[1][k], b1, accH[1][1], 0, 0, 0);
    }

    // exact GELU + bf16 -> swizzled LDS (double buffer by loop index)
    ushort* lb = lh[cc & 1];
#pragma unroll
    for (int fc = 0; fc < 2; ++fc) {
      float bv = bias1[e*HID + h0 + wc*32 + fc*16 + l15];
      int col = wc*32 + fc*16 + l15;
#pragma unroll
      for (int fr = 0; fr < 2; ++fr)
#pragma unroll
        for (int j = 0; j < 4; ++j) {
          int row = wr*32 + fr*16 + lr4 + j;
          float v = accH[fr][fc][j] + bv;
          v = 0.5f * v * (1.0f + erff(v * 0.70710678118654752f));
          *(ushort*)((char*)lb + row*128 + ((col*2) ^ lh_slot(row))) = f2bf(v);
        }
    }
    __syncthreads();

    // GEMM2: y[64x256] += h[64x64] @ W2[64x256], B from prefetched regs
#pragma unroll
    for (int k2 = 0; k2 < 2; ++k2) {
      bf16x8 a2[4];
#pragma unroll
      for (int fr = 0; fr < 4; ++fr) {
        int row = fr*16 + l15;
        a2[fr] = *(const bf16x8*)((const char*)lb + row*128 + (((k2*32 + lk8)*2) ^ sl2[fr]));
      }
#pragma unroll
      for (int fr = 0; fr < 4; ++fr)
#pragma unroll
        for (int fc = 0; fc < 4; ++fc)
          accY[fr][fc] = __builtin_amdgcn_mfma_f32_16x16x32_bf16(a2[fr], bw[k2][fc], accY[fr][fc], 0, 0, 0);
    }
  }

  // epilogue: out[t] += w * (y + b2)
  float b2v[4];
#pragma unroll
  for (int fc = 0; fc < 4; ++fc) b2v[fc] = bias2[e*DIM + wid*64 + fc*16 + l15];
#pragma unroll
  for (int fr = 0; fr < 4; ++fr) {
#pragma unroll
    for (int j = 0; j < 4; ++j) {
      int r = fr*16 + lr4 + j;
      if (r < rows) {
        int t = etok[r];
        float w = ewgt[r];
#pragma unroll
        for (int fc = 0; fc < 4; ++fc)
          atomicAdd(out + (size_t)t * DIM + wid*64 + fc*16 + l15,
                    w * (accY[fr][fc][j] + b2v[fc]));
      }
    }
  }
}

// ---------- DIAGNOSTIC PROBE (r8 only): identical skeleton, NO per-chunk W
// loads (const frags), NO epilogue writes. Writes nothing (never-taken store
// keeps MFMA chain live). Read-out: present in top-5 ~ real => skeleton-bound;
// absent => W-load/epilogue path dominates the real kernel. ----
__global__ __launch_bounds__(256, 2) void k_moe_probe(
    const float* __restrict__ x,
    const ushort* __restrict__ w1t, const ushort* __restrict__ w2t,
    const float* __restrict__ bias1,
    const int* __restrict__ cnt, const int* __restrict__ tok,
    float* __restrict__ sink)
{
  int e    = blockIdx.x & 7;
  int tile = blockIdx.x >> 3;
  int c = cnt[e];
  int row0 = tile * BM;
  if (row0 >= c) return;
  int rows = min(BM, c - row0);

  __shared__ ushort lx[BM * DIM];
  __shared__ ushort lh[2][BM * BH];

  int tid  = threadIdx.x;
  int lane = tid & 63;
  int wid  = tid >> 6;
  const int l15 = lane & 15;
  const int lk8 = (lane >> 4) * 8;
  const int lr4 = (lane >> 4) * 4;
  const int wr = wid >> 1, wc = wid & 1;

  const int* etok = tok + e * N_TOK + row0;

  for (int f = tid; f < BM * (DIM/4); f += 256) {
    int r = f >> 6, c4 = f & 63;
    int t = etok[min(r, rows - 1)];
    float4 v = *(const float4*)(x + (size_t)t * DIM + c4 * 4);
    ushort4 b;
    b.x = f2bf(v.x); b.y = f2bf(v.y); b.z = f2bf(v.z); b.w = f2bf(v.w);
    *(ushort4*)((char*)lx + r * 512 + ((c4 * 8) ^ lx_slot(r))) = b;
  }
  __syncthreads();

  bf16x8 areg[2][8];
#pragma unroll
  for (int fr = 0; fr < 2; ++fr) {
    int row = wr*32 + fr*16 + l15;
#pragma unroll
    for (int k = 0; k < 8; ++k)
      areg[fr][k] = *(const bf16x8*)((const char*)lx + row*512
                      + (((k*32 + lk8)*2) ^ lx_slot(row)));
  }

  f32x4 accY[4][4];
#pragma unroll
  for (int i = 0; i < 4; ++i)
#pragma unroll
    for (int j = 0; j < 4; ++j) accY[i][j] = (f32x4){0.f,0.f,0.f,0.f};

  const ushort* W1e = w1t + (size_t)e * HID * DIM;
  const ushort* W2e = w2t + (size_t)e * DIM * HID;

  // constant fragments, loaded ONCE (no per-chunk W traffic)
  bf16x8 cb0 = *(const bf16x8*)(W1e + (size_t)(wc*32 +      l15) * DIM + lk8);
  bf16x8 cb1 = *(const bf16x8*)(W1e + (size_t)(wc*32 + 16 + l15) * DIM + lk8);
  bf16x8 cbw = *(const bf16x8*)(W2e + (size_t)(wid*64 +     l15) * HID + lk8);

  int sl2[4];
#pragma unroll
  for (int fr = 0; fr < 4; ++fr) sl2[fr] = lh_slot(fr*16 + l15);

  for (int cc = 0; cc < HID / BH; ++cc) {
    int h0 = cc * BH;
    f32x4 accH[2][2];
#pragma unroll
    for (int i = 0; i < 2; ++i)
#pragma unroll
      for (int j = 0; j < 2; ++j) accH[i][j] = (f32x4){0.f,0.f,0.f,0.f};

#pragma unroll
    for (int k = 0; k < 8; ++k) {
      accH[0][0] = __builtin_amdgcn_mfma_f32_16x16x32_bf16(areg[0][k], cb0, accH[0][0], 0, 0, 0);
      accH[1][0] = __builtin_amdgcn_mfma_f32_16x16x32_bf16(areg[1][k], cb0, accH[1][0], 0, 0, 0);
      accH[0][1] = __builtin_amdgcn_mfma_f32_16x16x32_bf16(areg[0][k], cb1, accH[0][1], 0, 0, 0);
      accH[1][1] = __builtin_amdgcn_mfma_f32_16x16x32_bf16(areg[1][k], cb1, accH[1][1], 0, 0, 0);
    }

    ushort* lb = lh[cc & 1];
#pragma unroll
    for (int fc = 0; fc < 2; ++fc) {
      float bv = bias1[e*HID + h0 + wc*32 + fc*16 + l15];
      int col = wc*32 + fc*16 + l15;
#pragma unroll
      for (int fr = 0; fr < 2; ++fr)
#pragma unroll
        for (int j = 0; j < 4; ++j) {
          int row = wr*32 + fr*16 + lr4 + j;
          float v = accH[fr][fc][j] + bv;
          v = 0.5f * v * (1.0f + erff(v * 0.70710678118654752f));
          *(ushort*)((char*)lb + row*128 + ((col*2) ^ lh_slot(row))) = f2bf(v);
        }
    }
    __syncthreads();

#pragma unroll
    for (int k2 = 0; k2 < 2; ++k2) {
      bf16x8 a2[4];
#pragma unroll
      for (int fr = 0; fr < 4; ++fr) {
        int row = fr*16 + l15;
        a2[fr] = *(const bf16x8*)((const char*)lb + row*128 + (((k2*32 + lk8)*2) ^ sl2[fr]));
      }
#pragma unroll
      for (int fr = 0; fr < 4; ++fr)
#pragma unroll
        for (int fc = 0; fc < 4; ++fc)
          accY[fr][fc] = __builtin_amdgcn_mfma_f32_16x16x32_bf16(a2[fr], cbw, accY[fr][fc], 0, 0, 0);
    }
  }

  // keep the MFMA chain live without writing (condition never true at runtime,
  // unprovable at compile time)
  float s = 0.f;
#pragma unroll
  for (int fr = 0; fr < 4; ++fr)
#pragma unroll
    for (int fc = 0; fc < 4; ++fc)
#pragma unroll
      for (int j = 0; j < 4; ++j) s += accY[fr][fc][j];
  if (s == 1.2345e30f) sink[tid] = s;
}

extern "C" void kernel_launch(void* const* d_in, const int* in_sizes, int n_in,
                              void* d_out, int out_size, void* d_ws, size_t ws_size,
                              hipStream_t stream)
{
  const float* x    = (const float*)d_in[0];
  const float* grad = (const float*)d_in[1];
  const float* Wr   = (const float*)d_in[2];
  const float* br   = (const float*)d_in[3];
  const float* W1   = (const float*)d_in[4];
  const float* b1   = (const float*)d_in[5];
  const float* W2   = (const float*)d_in[6];
  const float* b2   = (const float*)d_in[7];
  float* out   = (float*)d_out;
  float* probs = out + (size_t)N_TOK * DIM;

  char* wsb = (char*)d_ws;
  int*    cnt = (int*)wsb;                                        // 32 B
  int*    tok = (int*)   (wsb + 4096);                            // 1 MB
  float*  wgt = (float*) (wsb + 4096 + (size_t)NEXP*N_TOK*4);     // 1 MB
  ushort* w1t = (ushort*)(wsb + 4096 + (size_t)NEXP*N_TOK*8);     // 4 MB
  ushort* w2t = w1t + (size_t)NEXP * HID * DIM;                   // 4 MB

  hipMemsetAsync(d_out, 0, (size_t)N_TOK * DIM * sizeof(float), stream);
  hipMemsetAsync(cnt, 0, NEXP * sizeof(int), stream);

  k_transpose_cast<<<dim3(HID/32, DIM/32, NEXP), dim3(32, 8), 0, stream>>>(W1, w1t, DIM, HID);
  k_transpose_cast<<<dim3(DIM/32, HID/32, NEXP), dim3(32, 8), 0, stream>>>(W2, w2t, HID, DIM);
  k_router<<<N_TOK/256, 256, 0, stream>>>(x, grad, Wr, br, probs, cnt, tok, wgt);
  k_moe<<<NEXP*MAXT, 256, 0, stream>>>(x, w1t, w2t, b1, b2, cnt, tok, wgt, out);
  // diagnostic probe (writes nothing; wgt passed only as a dead sink address)
  k_moe_probe<<<NEXP*MAXT, 256, 0, stream>>>(x, w1t, w2t, b1, cnt, tok, wgt);
}

// Round 9
// 260.230 us; speedup vs baseline: 1.8086x; 1.8086x over previous
//
#include <hip/hip_runtime.h>
#include <hip/hip_bf16.h>
#include <cmath>

#define N_TOK 32768
#define DIM   256
#define NEXP  8
#define HID   1024
#define BM    64
#define BH    64
#define MAXT  512   // MAXT*BM == N_TOK: covers worst-case expert load

typedef short bf16x8 __attribute__((ext_vector_type(8)));
typedef float f32x4  __attribute__((ext_vector_type(4)));

__device__ __forceinline__ ushort f2bf(float f) {
  unsigned u = __builtin_bit_cast(unsigned, f);
  u += 0x7fffu + ((u >> 16) & 1u);   // RNE
  return (ushort)(u >> 16);
}

// Fast exact-GELU: erf via Abramowitz-Stegun 7.1.26 (|err| <= 1.5e-7, far
// below the 8.5e-3 harness threshold; bf16 input rounding dominates anyway).
__device__ __forceinline__ float gelu_f(float v) {
  float z  = 0.70710678118654752f * v;
  float az = fabsf(z);
  float t  = 1.0f / (1.0f + 0.3275911f * az);
  float y  = 1.0f - t*(0.254829592f + t*(-0.284496736f + t*(1.421413741f
                 + t*(-1.453152027f + t*1.061405429f)))) * __expf(-az*az);
  float er = (z < 0.f) ? -y : y;
  return 0.5f * v * (1.0f + er);
}

// lh swizzle (128B rows): 16B-slot XOR, max 112 < 128 -> bijective in-row.
__device__ __forceinline__ int lh_slot(int row) {
  return ((row ^ (row >> 3)) & 7) << 4;
}
// lx swizzle (512B rows): (r&7)<<4, max 112 < 512, bijective.
__device__ __forceinline__ int lx_slot(int row) {
  return (row & 7) << 4;
}

// ---------- transpose + cast: src[E][R][C] f32 -> dst[E][C][R] bf16 ----------
__global__ __launch_bounds__(256) void k_transpose_cast(
    const float* __restrict__ src, ushort* __restrict__ dst, int R, int C)
{
  __shared__ float tile[32][33];
  int e = blockIdx.z, rb = blockIdx.y, cb = blockIdx.x;
  int tx = threadIdx.x, ty = threadIdx.y;           // 32 x 8
  const float* s = src + (size_t)e * R * C;
  ushort* d = dst + (size_t)e * R * C;
#pragma unroll
  for (int j = 0; j < 4; ++j)
    tile[ty + 8*j][tx] = s[(size_t)(rb*32 + ty + 8*j) * C + cb*32 + tx];
  __syncthreads();
#pragma unroll
  for (int j = 0; j < 4; ++j)
    d[(size_t)(cb*32 + ty + 8*j) * R + rb*32 + tx] = f2bf(tile[tx][ty + 8*j]);
}

// ---------- router: fp64 logits, softmax, top-2, bucket scatter ----------
__global__ __launch_bounds__(256) void k_router(
    const float* __restrict__ x, const float* __restrict__ grad,
    const float* __restrict__ Wr, const float* __restrict__ br,
    float* __restrict__ probs_out,
    int* __restrict__ cnt, int* __restrict__ tok, float* __restrict__ wgt)
{
  __shared__ float xt[256][33];
  __shared__ float wrs[257*8];
  __shared__ float brs[8];
  __shared__ int lcnt[8], lbase[8];
  int tid = threadIdx.x;
  int n = blockIdx.x * 256 + tid;

  for (int i = tid; i < 257*8; i += 256) wrs[i] = Wr[i];
  if (tid < 8) { brs[tid] = br[tid]; lcnt[tid] = 0; }

  double acc[8] = {0,0,0,0,0,0,0,0};
  for (int ch = 0; ch < 8; ++ch) {
    __syncthreads();
    for (int f = tid; f < 2048; f += 256) {
      int r = f >> 3, c0 = (f & 7) * 4;
      float4 v = *(const float4*)(x + (size_t)(blockIdx.x*256 + r)*DIM + ch*32 + c0);
      xt[r][c0] = v.x; xt[r][c0+1] = v.y; xt[r][c0+2] = v.z; xt[r][c0+3] = v.w;
    }
    __syncthreads();
#pragma unroll 4
    for (int c = 0; c < 32; ++c) {
      double xv = (double)xt[tid][c];
      const float* wr = &wrs[(ch*32 + c)*8];
#pragma unroll
      for (int e = 0; e < 8; ++e) acc[e] += xv * (double)wr[e];
    }
  }
  double g = (double)grad[n];
  double lg[8];
#pragma unroll
  for (int e = 0; e < 8; ++e) lg[e] = acc[e] + g*(double)wrs[256*8+e] + (double)brs[e];
  double m = lg[0];
#pragma unroll
  for (int e = 1; e < 8; ++e) m = lg[e] > m ? lg[e] : m;
  double p[8], s = 0.0;
#pragma unroll
  for (int e = 0; e < 8; ++e) { p[e] = exp(lg[e]-m); s += p[e]; }
  double inv = 1.0/s;
#pragma unroll
  for (int e = 0; e < 8; ++e) probs_out[(size_t)n*8 + e] = (float)(p[e]*inv);

  int i0 = 0;
#pragma unroll
  for (int e = 1; e < 8; ++e) if (lg[e] > lg[i0]) i0 = e;
  int i1 = (i0 == 0) ? 1 : 0;
#pragma unroll
  for (int e = 0; e < 8; ++e) if (e != i0 && lg[e] > lg[i1]) i1 = e;
  float w0 = (float)(p[i0]*inv), w1 = (float)(p[i1]*inv);

  int p0 = atomicAdd(&lcnt[i0], 1);
  int p1 = atomicAdd(&lcnt[i1], 1);
  __syncthreads();
  if (tid < 8) lbase[tid] = atomicAdd(&cnt[tid], lcnt[tid]);
  __syncthreads();
  tok[i0*N_TOK + lbase[i0] + p0] = n;  wgt[i0*N_TOK + lbase[i0] + p0] = w0;
  tok[i1*N_TOK + lbase[i1] + p1] = n;  wgt[i1*N_TOK + lbase[i1] + p1] = w1;
}

// ---------- fused gathered expert MLP ----------
// (256,2): VGPR cap 256/wave; tighter caps spill to scratch (FETCH 530-938 MB).
// e = bid&7: XCD x runs only expert x -> weights L2-resident (FETCH 40 MB).
// r8 probe: skeleton-without-W-loads = ~100-130us vs real 321us -> W-load
// exposure dominates. r9: W1 chunk tile staged to LDS via global_load_lds
// (source-side XOR swizzle, LDS linear - m173 pattern), staged for chunk c+1
// during GEMM2(c); W2 stays reg-prefetched; bias1 in LDS; fast erf.
__global__ __launch_bounds__(256, 2) void k_moe(
    const float* __restrict__ x,
    const ushort* __restrict__ w1t,   // [E][H][D] bf16 (transposed)
    const ushort* __restrict__ w2t,   // [E][D][H] bf16 (transposed)
    const float* __restrict__ bias1,  // [E][H]
    const float* __restrict__ bias2,  // [E][D]
    const int* __restrict__ cnt, const int* __restrict__ tok,
    const float* __restrict__ wgt,
    float* __restrict__ out)
{
  int e    = blockIdx.x & 7;
  int tile = blockIdx.x >> 3;
  int c = cnt[e];
  int row0 = tile * BM;
  if (row0 >= c) return;
  int rows = min(BM, c - row0);
  int phase = tile & 15;              // stagger concurrent blocks across W chunks

  __shared__ ushort lx[BM * DIM];     // 32 KB x tile (swizzled rows)
  __shared__ ushort w1l[BH * DIM];    // 32 KB W1 chunk tile (src-swizzled, linear dest)
  __shared__ ushort lh[BM * BH];      // 8 KB h tile (single buffer, 2 barriers/chunk)
  __shared__ float  lb1[HID];         // 4 KB bias1
  // total 76 KB -> 2 blocks/CU

  int tid  = threadIdx.x;
  int lane = tid & 63;
  int wid  = tid >> 6;
  const int l15 = lane & 15;
  const int lk8 = (lane >> 4) * 8;
  const int lr4 = (lane >> 4) * 4;
  const int wr = wid >> 1, wc = wid & 1;   // 2x2 wave grid for GEMM1

  const int*   etok = tok + e * N_TOK + row0;
  const float* ewgt = wgt + e * N_TOK + row0;
  const ushort* W1e = w1t + (size_t)e * HID * DIM;
  const ushort* W2e = w2t + (size_t)e * DIM * HID;

  // ---- prologue staging ----
  // x rows -> bf16 swizzled LDS (coalesced: one full 1KB row per wave-inst)
  for (int f = tid; f < BM * (DIM/4); f += 256) {
    int r = f >> 6, c4 = f & 63;
    int t = etok[min(r, rows - 1)];
    float4 v = *(const float4*)(x + (size_t)t * DIM + c4 * 4);
    ushort4 b;
    b.x = f2bf(v.x); b.y = f2bf(v.y); b.z = f2bf(v.z); b.w = f2bf(v.w);
    *(ushort4*)((char*)lx + r * 512 + ((c4 * 8) ^ lx_slot(r))) = b;
  }
  // bias1 -> LDS
#pragma unroll
  for (int i = 0; i < 4; ++i) lb1[i*256 + tid] = bias1[e*HID + i*256 + tid];
  // W1 tile for first chunk -> LDS (async, drained at the syncthreads below).
  // Source-side swizzle: LDS unit u (16B) holds global slot (s ^ (r&7)) of row r.
  {
    int h0 = ((0 + phase) & 15) * BH;
#pragma unroll
    for (int i = 0; i < 8; ++i) {
      int u = i*256 + tid;
      int r = u >> 5, s = u & 31;
      const ushort* g = W1e + (size_t)(h0 + r) * DIM + ((s ^ (r & 7)) * 8);
      __builtin_amdgcn_global_load_lds(
          (const __attribute__((address_space(1))) unsigned int*)g,
          (__attribute__((address_space(3))) unsigned int*)(w1l + u*8),
          16, 0, 0);
    }
  }
  __syncthreads();

  // ---- hoist A-fragments to registers once ----
  bf16x8 areg[2][8];
#pragma unroll
  for (int fr = 0; fr < 2; ++fr) {
    int row = wr*32 + fr*16 + l15;
#pragma unroll
    for (int k = 0; k < 8; ++k)
      areg[fr][k] = *(const bf16x8*)((const char*)lx + row*512
                      + (((k*32 + lk8)*2) ^ lx_slot(row)));
  }

  f32x4 accY[4][4];
#pragma unroll
  for (int i = 0; i < 4; ++i)
#pragma unroll
    for (int j = 0; j < 4; ++j) accY[i][j] = (f32x4){0.f,0.f,0.f,0.f};

  int sl2[4];
#pragma unroll
  for (int fr = 0; fr < 4; ++fr) sl2[fr] = lh_slot(fr*16 + l15);

  // W1 LDS fragment addressing (ushort units): unit = row*32 + (s ^ (row&7))
  const int b0row = wc*32 + l15;            // b1 row = b0row+16, same (row&7)
  const int bxor  = (b0row & 7);

  for (int cc = 0; cc < HID / BH; ++cc) {
    int chunk = (cc + phase) & 15;
    int h0 = chunk * BH;

    // prefetch this chunk's W2 B-fragments (regs; consumed after barrier A)
    bf16x8 bw[2][4];
#pragma unroll
    for (int k2 = 0; k2 < 2; ++k2)
#pragma unroll
      for (int fc = 0; fc < 4; ++fc)
        bw[k2][fc] = *(const bf16x8*)(W2e + (size_t)(wid*64 + fc*16 + l15) * HID
                                      + h0 + k2*32 + lk8);

    f32x4 accH[2][2];
#pragma unroll
    for (int i = 0; i < 2; ++i)
#pragma unroll
      for (int j = 0; j < 2; ++j) accH[i][j] = (f32x4){0.f,0.f,0.f,0.f};

    // GEMM1: h[64x64] = x[64x256] @ W1[256x64]; B from w1l (conflict-free)
#pragma unroll
    for (int k = 0; k < 8; ++k) {
      int s = k*4 + (lane >> 4);
      bf16x8 b0 = *(const bf16x8*)(w1l + ((b0row     )*32 + (s ^ bxor))*8);
      bf16x8 b1 = *(const bf16x8*)(w1l + ((b0row + 16)*32 + (s ^ bxor))*8);
      accH[0][0] = __builtin_amdgcn_mfma_f32_16x16x32_bf16(areg[0][k], b0, accH[0][0], 0, 0, 0);
      accH[1][0] = __builtin_amdgcn_mfma_f32_16x16x32_bf16(areg[1][k], b0, accH[1][0], 0, 0, 0);
      accH[0][1] = __builtin_amdgcn_mfma_f32_16x16x32_bf16(areg[0][k], b1, accH[0][1], 0, 0, 0);
      accH[1][1] = __builtin_amdgcn_mfma_f32_16x16x32_bf16(areg[1][k], b1, accH[1][1], 0, 0, 0);
    }

    // GELU + bf16 -> swizzled lh
#pragma unroll
    for (int fc = 0; fc < 2; ++fc) {
      int col = wc*32 + fc*16 + l15;
      float bv = lb1[h0 + col];
#pragma unroll
      for (int fr = 0; fr < 2; ++fr)
#pragma unroll
        for (int j = 0; j < 4; ++j) {
          int row = wr*32 + fr*16 + lr4 + j;
          float v = gelu_f(accH[fr][fc][j] + bv);
          *(ushort*)((char*)lh + row*128 + ((col*2) ^ lh_slot(row))) = f2bf(v);
        }
    }
    __syncthreads();   // barrier A: lh visible; w1l fully consumed

    // stage W1 for NEXT chunk (async; drains at barrier B, hidden under GEMM2)
    if (cc < HID/BH - 1) {
      int nh0 = ((cc + 1 + phase) & 15) * BH;
#pragma unroll
      for (int i = 0; i < 8; ++i) {
        int u = i*256 + tid;
        int r = u >> 5, s = u & 31;
        const ushort* g = W1e + (size_t)(nh0 + r) * DIM + ((s ^ (r & 7)) * 8);
        __builtin_amdgcn_global_load_lds(
            (const __attribute__((address_space(1))) unsigned int*)g,
            (__attribute__((address_space(3))) unsigned int*)(w1l + u*8),
            16, 0, 0);
      }
    }

    // GEMM2: y[64x256] += h[64x64] @ W2[64x256]
#pragma unroll
    for (int k2 = 0; k2 < 2; ++k2) {
      bf16x8 a2[4];
#pragma unroll
      for (int fr = 0; fr < 4; ++fr) {
        int row = fr*16 + l15;
        a2[fr] = *(const bf16x8*)((const char*)lh + row*128 + (((k2*32 + lk8)*2) ^ sl2[fr]));
      }
#pragma unroll
      for (int fr = 0; fr < 4; ++fr)
#pragma unroll
        for (int fc = 0; fc < 4; ++fc)
          accY[fr][fc] = __builtin_amdgcn_mfma_f32_16x16x32_bf16(a2[fr], bw[k2][fc], accY[fr][fc], 0, 0, 0);
    }
    __syncthreads();   // barrier B: w1l staged (per-wave vmcnt drained) + lh reusable
  }

  // epilogue: out[t] += w * (y + b2)
  float b2v[4];
#pragma unroll
  for (int fc = 0; fc < 4; ++fc) b2v[fc] = bias2[e*DIM + wid*64 + fc*16 + l15];
#pragma unroll
  for (int fr = 0; fr < 4; ++fr) {
#pragma unroll
    for (int j = 0; j < 4; ++j) {
      int r = fr*16 + lr4 + j;
      if (r < rows) {
        int t = etok[r];
        float w = ewgt[r];
#pragma unroll
        for (int fc = 0; fc < 4; ++fc)
          atomicAdd(out + (size_t)t * DIM + wid*64 + fc*16 + l15,
                    w * (accY[fr][fc][j] + b2v[fc]));
      }
    }
  }
}

extern "C" void kernel_launch(void* const* d_in, const int* in_sizes, int n_in,
                              void* d_out, int out_size, void* d_ws, size_t ws_size,
                              hipStream_t stream)
{
  const float* x    = (const float*)d_in[0];
  const float* grad = (const float*)d_in[1];
  const float* Wr   = (const float*)d_in[2];
  const float* br   = (const float*)d_in[3];
  const float* W1   = (const float*)d_in[4];
  const float* b1   = (const float*)d_in[5];
  const float* W2   = (const float*)d_in[6];
  const float* b2   = (const float*)d_in[7];
  float* out   = (float*)d_out;
  float* probs = out + (size_t)N_TOK * DIM;

  char* wsb = (char*)d_ws;
  int*    cnt = (int*)wsb;                                        // 32 B
  int*    tok = (int*)   (wsb + 4096);                            // 1 MB
  float*  wgt = (float*) (wsb + 4096 + (size_t)NEXP*N_TOK*4);     // 1 MB
  ushort* w1t = (ushort*)(wsb + 4096 + (size_t)NEXP*N_TOK*8);     // 4 MB
  ushort* w2t = w1t + (size_t)NEXP * HID * DIM;                   // 4 MB

  hipMemsetAsync(d_out, 0, (size_t)N_TOK * DIM * sizeof(float), stream);
  hipMemsetAsync(cnt, 0, NEXP * sizeof(int), stream);

  k_transpose_cast<<<dim3(HID/32, DIM/32, NEXP), dim3(32, 8), 0, stream>>>(W1, w1t, DIM, HID);
  k_transpose_cast<<<dim3(DIM/32, HID/32, NEXP), dim3(32, 8), 0, stream>>>(W2, w2t, HID, DIM);
  k_router<<<N_TOK/256, 256, 0, stream>>>(x, grad, Wr, br, probs, cnt, tok, wgt);
  k_moe<<<NEXP*MAXT, 256, 0, stream>>>(x, w1t, w2t, b1, b2, cnt, tok, wgt, out);
}

// Round 10
// 236.914 us; speedup vs baseline: 1.9866x; 1.0984x over previous
//
#include <hip/hip_runtime.h>
#include <hip/hip_bf16.h>
#include <cmath>

#define N_TOK 32768
#define DIM   256
#define NEXP  8
#define HID   1024
#define BM    64
#define BH    64
#define MAXT  512   // MAXT*BM == N_TOK: covers worst-case expert load

typedef short bf16x8 __attribute__((ext_vector_type(8)));
typedef float f32x4  __attribute__((ext_vector_type(4)));

__device__ __forceinline__ ushort f2bf(float f) {
  unsigned u = __builtin_bit_cast(unsigned, f);
  u += 0x7fffu + ((u >> 16) & 1u);   // RNE
  return (ushort)(u >> 16);
}

// Fast exact-GELU: erf via Abramowitz-Stegun 7.1.26 (|err| <= 1.5e-7 << 8.5e-3).
__device__ __forceinline__ float gelu_f(float v) {
  float z  = 0.70710678118654752f * v;
  float az = fabsf(z);
  float t  = 1.0f / (1.0f + 0.3275911f * az);
  float y  = 1.0f - t*(0.254829592f + t*(-0.284496736f + t*(1.421413741f
                 + t*(-1.453152027f + t*1.061405429f)))) * __expf(-az*az);
  float er = (z < 0.f) ? -y : y;
  return 0.5f * v * (1.0f + er);
}

// lh swizzle (128B rows): 16B-slot XOR, max 112 < 128 -> bijective in-row.
__device__ __forceinline__ int lh_slot(int row) {
  return ((row ^ (row >> 3)) & 7) << 4;
}
// lx swizzle (512B rows): (r&7)<<4, max 112 < 512, bijective.
__device__ __forceinline__ int lx_slot(int row) {
  return (row & 7) << 4;
}

// ---------- transpose + cast: src[E][R][C] f32 -> dst[E][C][R] bf16 ----------
__global__ __launch_bounds__(256) void k_transpose_cast(
    const float* __restrict__ src, ushort* __restrict__ dst, int R, int C)
{
  __shared__ float tile[32][33];
  int e = blockIdx.z, rb = blockIdx.y, cb = blockIdx.x;
  int tx = threadIdx.x, ty = threadIdx.y;           // 32 x 8
  const float* s = src + (size_t)e * R * C;
  ushort* d = dst + (size_t)e * R * C;
#pragma unroll
  for (int j = 0; j < 4; ++j)
    tile[ty + 8*j][tx] = s[(size_t)(rb*32 + ty + 8*j) * C + cb*32 + tx];
  __syncthreads();
#pragma unroll
  for (int j = 0; j < 4; ++j)
    d[(size_t)(cb*32 + ty + 8*j) * R + rb*32 + tx] = f2bf(tile[tx][ty + 8*j]);
}

// ---------- router: fp64 logits, softmax, top-2, bucket scatter ----------
// tok entry packs the top-k slot in bit 30: n | (slot<<30).
__global__ __launch_bounds__(256) void k_router(
    const float* __restrict__ x, const float* __restrict__ grad,
    const float* __restrict__ Wr, const float* __restrict__ br,
    float* __restrict__ probs_out,
    int* __restrict__ cnt, int* __restrict__ tok, float* __restrict__ wgt)
{
  __shared__ float xt[256][33];
  __shared__ float wrs[257*8];
  __shared__ float brs[8];
  __shared__ int lcnt[8], lbase[8];
  int tid = threadIdx.x;
  int n = blockIdx.x * 256 + tid;

  for (int i = tid; i < 257*8; i += 256) wrs[i] = Wr[i];
  if (tid < 8) { brs[tid] = br[tid]; lcnt[tid] = 0; }

  double acc[8] = {0,0,0,0,0,0,0,0};
  for (int ch = 0; ch < 8; ++ch) {
    __syncthreads();
    for (int f = tid; f < 2048; f += 256) {
      int r = f >> 3, c0 = (f & 7) * 4;
      float4 v = *(const float4*)(x + (size_t)(blockIdx.x*256 + r)*DIM + ch*32 + c0);
      xt[r][c0] = v.x; xt[r][c0+1] = v.y; xt[r][c0+2] = v.z; xt[r][c0+3] = v.w;
    }
    __syncthreads();
#pragma unroll 4
    for (int c = 0; c < 32; ++c) {
      double xv = (double)xt[tid][c];
      const float* wr = &wrs[(ch*32 + c)*8];
#pragma unroll
      for (int e = 0; e < 8; ++e) acc[e] += xv * (double)wr[e];
    }
  }
  double g = (double)grad[n];
  double lg[8];
#pragma unroll
  for (int e = 0; e < 8; ++e) lg[e] = acc[e] + g*(double)wrs[256*8+e] + (double)brs[e];
  double m = lg[0];
#pragma unroll
  for (int e = 1; e < 8; ++e) m = lg[e] > m ? lg[e] : m;
  double p[8], s = 0.0;
#pragma unroll
  for (int e = 0; e < 8; ++e) { p[e] = exp(lg[e]-m); s += p[e]; }
  double inv = 1.0/s;
#pragma unroll
  for (int e = 0; e < 8; ++e) probs_out[(size_t)n*8 + e] = (float)(p[e]*inv);

  int i0 = 0;
#pragma unroll
  for (int e = 1; e < 8; ++e) if (lg[e] > lg[i0]) i0 = e;
  int i1 = (i0 == 0) ? 1 : 0;
#pragma unroll
  for (int e = 0; e < 8; ++e) if (e != i0 && lg[e] > lg[i1]) i1 = e;
  float w0 = (float)(p[i0]*inv), w1 = (float)(p[i1]*inv);

  int p0 = atomicAdd(&lcnt[i0], 1);
  int p1 = atomicAdd(&lcnt[i1], 1);
  __syncthreads();
  if (tid < 8) lbase[tid] = atomicAdd(&cnt[tid], lcnt[tid]);
  __syncthreads();
  tok[i0*N_TOK + lbase[i0] + p0] = n;              wgt[i0*N_TOK + lbase[i0] + p0] = w0;
  tok[i1*N_TOK + lbase[i1] + p1] = n | (1 << 30);  wgt[i1*N_TOK + lbase[i1] + p1] = w1;
}

// ---------- fused gathered expert MLP ----------
// (256,2): VGPR cap 256/wave; tighter caps spill to scratch (FETCH 530-938 MB).
// e = bid&7: XCD x runs only expert x -> weights L2-resident.
// r10: W1 double-buffered (lx region reused after areg hoist + barrier);
// stage for chunk c+1 issued at TOP of chunk c -> barrier-A drain covered by
// GEMM1+GELU (~800 cyc) not just GEMM2. Barrier B is vm-free.
// SLAB=1: slot0 -> plain stores to out, slot1 -> plain stores to slab
// (atomic-free; k_combine adds). SLAB=0: atomicAdd fallback.
template<int SLAB>
__global__ __launch_bounds__(256, 2) void k_moe(
    const float* __restrict__ x,
    const ushort* __restrict__ w1t,   // [E][H][D] bf16 (transposed)
    const ushort* __restrict__ w2t,   // [E][D][H] bf16 (transposed)
    const float* __restrict__ bias1,  // [E][H]
    const float* __restrict__ bias2,  // [E][D]
    const int* __restrict__ cnt, const int* __restrict__ tok,
    const float* __restrict__ wgt,
    float* __restrict__ out, float* __restrict__ slab)
{
  int e    = blockIdx.x & 7;
  int tile = blockIdx.x >> 3;
  int c = cnt[e];
  int row0 = tile * BM;
  if (row0 >= c) return;
  int rows = min(BM, c - row0);
  int phase = tile & 15;              // stagger concurrent blocks across W chunks

  __shared__ ushort lsA[BM * DIM];    // 32 KB: x tile, then W1 buffer (odd chunks)
  __shared__ ushort lsB[BH * DIM];    // 32 KB: W1 buffer (even chunks)
  __shared__ ushort lh[BM * BH];      // 8 KB h tile
  __shared__ float  lb1[HID];         // 4 KB bias1
  // total 76 KB -> 2 blocks/CU (VGPR-bound at 2 anyway)

  int tid  = threadIdx.x;
  int lane = tid & 63;
  int wid  = tid >> 6;
  const int l15 = lane & 15;
  const int lk8 = (lane >> 4) * 8;
  const int lr4 = (lane >> 4) * 4;
  const int wr = wid >> 1, wc = wid & 1;   // 2x2 wave grid for GEMM1

  const int*   etok = tok + e * N_TOK + row0;
  const float* ewgt = wgt + e * N_TOK + row0;
  const ushort* W1e = w1t + (size_t)e * HID * DIM;
  const ushort* W2e = w2t + (size_t)e * DIM * HID;

  // ---- prologue: x -> lsA (swizzled), bias1 -> lb1, W1 chunk0 -> lsB ----
  for (int f = tid; f < BM * (DIM/4); f += 256) {
    int r = f >> 6, c4 = f & 63;
    int t = etok[min(r, rows - 1)] & 0xFFFF;
    float4 v = *(const float4*)(x + (size_t)t * DIM + c4 * 4);
    ushort4 b;
    b.x = f2bf(v.x); b.y = f2bf(v.y); b.z = f2bf(v.z); b.w = f2bf(v.w);
    *(ushort4*)((char*)lsA + r * 512 + ((c4 * 8) ^ lx_slot(r))) = b;
  }
#pragma unroll
  for (int i = 0; i < 4; ++i) lb1[i*256 + tid] = bias1[e*HID + i*256 + tid];
  {
    int h0 = (phase & 15) * BH;
#pragma unroll
    for (int i = 0; i < 8; ++i) {
      int u = i*256 + tid;
      int r = u >> 5, s = u & 31;
      const ushort* g = W1e + (size_t)(h0 + r) * DIM + ((s ^ (r & 7)) * 8);
      __builtin_amdgcn_global_load_lds(
          (const __attribute__((address_space(1))) unsigned int*)g,
          (__attribute__((address_space(3))) unsigned int*)(lsB + u*8),
          16, 0, 0);
    }
  }
  __syncthreads();

  // ---- hoist A-fragments to registers once ----
  bf16x8 areg[2][8];
#pragma unroll
  for (int fr = 0; fr < 2; ++fr) {
    int row = wr*32 + fr*16 + l15;
#pragma unroll
    for (int k = 0; k < 8; ++k)
      areg[fr][k] = *(const bf16x8*)((const char*)lsA + row*512
                      + (((k*32 + lk8)*2) ^ lx_slot(row)));
  }
  __syncthreads();   // all waves' areg reads done before lsA is restaged as W1

  f32x4 accY[4][4];
#pragma unroll
  for (int i = 0; i < 4; ++i)
#pragma unroll
    for (int j = 0; j < 4; ++j) accY[i][j] = (f32x4){0.f,0.f,0.f,0.f};

  int sl2[4];
#pragma unroll
  for (int fr = 0; fr < 4; ++fr) sl2[fr] = lh_slot(fr*16 + l15);

  // W1 LDS fragment addressing (ushort units): unit = row*32 + (s ^ (row&7))
  const int b0row = wc*32 + l15;            // b1 row = b0row+16, same (row&7)
  const int bxor  = (b0row & 7);

  for (int cc = 0; cc < HID / BH; ++cc) {
    int chunk = (cc + phase) & 15;
    int h0 = chunk * BH;
    ushort* cur = (cc & 1) ? lsA : lsB;
    ushort* nxt = (cc & 1) ? lsB : lsA;

    // stage W1 for chunk cc+1 FIRST: its vmcnt-drain at barrier A is covered
    // by GEMM1 + GELU
    if (cc < HID/BH - 1) {
      int nh0 = ((cc + 1 + phase) & 15) * BH;
#pragma unroll
      for (int i = 0; i < 8; ++i) {
        int u = i*256 + tid;
        int r = u >> 5, s = u & 31;
        const ushort* g = W1e + (size_t)(nh0 + r) * DIM + ((s ^ (r & 7)) * 8);
        __builtin_amdgcn_global_load_lds(
            (const __attribute__((address_space(1))) unsigned int*)g,
            (__attribute__((address_space(3))) unsigned int*)(nxt + u*8),
            16, 0, 0);
      }
    }

    // W2 B-fragments to regs (consumed after barrier A -> covered)
    bf16x8 bw[2][4];
#pragma unroll
    for (int k2 = 0; k2 < 2; ++k2)
#pragma unroll
      for (int fc = 0; fc < 4; ++fc)
        bw[k2][fc] = *(const bf16x8*)(W2e + (size_t)(wid*64 + fc*16 + l15) * HID
                                      + h0 + k2*32 + lk8);

    f32x4 accH[2][2];
#pragma unroll
    for (int i = 0; i < 2; ++i)
#pragma unroll
      for (int j = 0; j < 2; ++j) accH[i][j] = (f32x4){0.f,0.f,0.f,0.f};

    // GEMM1: h[64x64] = x[64x256] @ W1[256x64]; B from cur (conflict-free)
#pragma unroll
    for (int k = 0; k < 8; ++k) {
      int s = k*4 + (lane >> 4);
      bf16x8 b0 = *(const bf16x8*)(cur + ((b0row     )*32 + (s ^ bxor))*8);
      bf16x8 b1 = *(const bf16x8*)(cur + ((b0row + 16)*32 + (s ^ bxor))*8);
      accH[0][0] = __builtin_amdgcn_mfma_f32_16x16x32_bf16(areg[0][k], b0, accH[0][0], 0, 0, 0);
      accH[1][0] = __builtin_amdgcn_mfma_f32_16x16x32_bf16(areg[1][k], b0, accH[1][0], 0, 0, 0);
      accH[0][1] = __builtin_amdgcn_mfma_f32_16x16x32_bf16(areg[0][k], b1, accH[0][1], 0, 0, 0);
      accH[1][1] = __builtin_amdgcn_mfma_f32_16x16x32_bf16(areg[1][k], b1, accH[1][1], 0, 0, 0);
    }

    // GELU + bf16 -> swizzled lh
#pragma unroll
    for (int fc = 0; fc < 2; ++fc) {
      int col = wc*32 + fc*16 + l15;
      float bv = lb1[h0 + col];
#pragma unroll
      for (int fr = 0; fr < 2; ++fr)
#pragma unroll
        for (int j = 0; j < 4; ++j) {
          int row = wr*32 + fr*16 + lr4 + j;
          float v = gelu_f(accH[fr][fc][j] + bv);
          *(ushort*)((char*)lh + row*128 + ((col*2) ^ lh_slot(row))) = f2bf(v);
        }
    }
    __syncthreads();   // barrier A: lh visible; stage + bw drained (covered)

    // GEMM2: y[64x256] += h[64x64] @ W2[64x256]
#pragma unroll
    for (int k2 = 0; k2 < 2; ++k2) {
      bf16x8 a2[4];
#pragma unroll
      for (int fr = 0; fr < 4; ++fr) {
        int row = fr*16 + l15;
        a2[fr] = *(const bf16x8*)((const char*)lh + row*128 + (((k2*32 + lk8)*2) ^ sl2[fr]));
      }
#pragma unroll
      for (int fr = 0; fr < 4; ++fr)
#pragma unroll
        for (int fc = 0; fc < 4; ++fc)
          accY[fr][fc] = __builtin_amdgcn_mfma_f32_16x16x32_bf16(a2[fr], bw[k2][fc], accY[fr][fc], 0, 0, 0);
    }
    __syncthreads();   // barrier B: lh reusable (vm-free -> cheap)
  }

  // epilogue: contribution = w * (y + b2)
  float b2v[4];
#pragma unroll
  for (int fc = 0; fc < 4; ++fc) b2v[fc] = bias2[e*DIM + wid*64 + fc*16 + l15];
#pragma unroll
  for (int fr = 0; fr < 4; ++fr) {
#pragma unroll
    for (int j = 0; j < 4; ++j) {
      int r = fr*16 + lr4 + j;
      if (r < rows) {
        int raw = etok[r];
        int t   = raw & 0xFFFF;
        float w = ewgt[r];
        if (SLAB) {
          // each (token,slot) written by exactly one block -> plain stores
          float* dst = ((raw >> 30) ? slab : out) + (size_t)t * DIM;
#pragma unroll
          for (int fc = 0; fc < 4; ++fc)
            dst[wid*64 + fc*16 + l15] = w * (accY[fr][fc][j] + b2v[fc]);
        } else {
#pragma unroll
          for (int fc = 0; fc < 4; ++fc)
            atomicAdd(out + (size_t)t * DIM + wid*64 + fc*16 + l15,
                      w * (accY[fr][fc][j] + b2v[fc]));
        }
      }
    }
  }
}

// out += slab (slab fully written: every token has exactly one slot-1 entry)
__global__ __launch_bounds__(256) void k_combine(
    float* __restrict__ out, const float* __restrict__ slab)
{
  int stride = gridDim.x * blockDim.x;
  for (int i = blockIdx.x * blockDim.x + threadIdx.x;
       i < N_TOK * DIM / 4; i += stride) {
    float4 a = ((const float4*)out)[i];
    float4 b = ((const float4*)slab)[i];
    a.x += b.x; a.y += b.y; a.z += b.z; a.w += b.w;
    ((float4*)out)[i] = a;
  }
}

extern "C" void kernel_launch(void* const* d_in, const int* in_sizes, int n_in,
                              void* d_out, int out_size, void* d_ws, size_t ws_size,
                              hipStream_t stream)
{
  const float* x    = (const float*)d_in[0];
  const float* grad = (const float*)d_in[1];
  const float* Wr   = (const float*)d_in[2];
  const float* br   = (const float*)d_in[3];
  const float* W1   = (const float*)d_in[4];
  const float* b1   = (const float*)d_in[5];
  const float* W2   = (const float*)d_in[6];
  const float* b2   = (const float*)d_in[7];
  float* out   = (float*)d_out;
  float* probs = out + (size_t)N_TOK * DIM;

  char* wsb = (char*)d_ws;
  int*    cnt = (int*)wsb;                                        // 32 B
  int*    tok = (int*)   (wsb + 4096);                            // 1 MB
  float*  wgt = (float*) (wsb + 4096 + (size_t)NEXP*N_TOK*4);     // 1 MB
  ushort* w1t = (ushort*)(wsb + 4096 + (size_t)NEXP*N_TOK*8);     // 4 MB
  ushort* w2t = w1t + (size_t)NEXP * HID * DIM;                   // 4 MB
  float*  slab = (float*)(wsb + (size_t)(16 << 20));              // 32 MB @ +16MB

  bool use_slab = ws_size >= ((size_t)(16 << 20) + (size_t)N_TOK * DIM * 4);

  hipMemsetAsync(d_out, 0, (size_t)N_TOK * DIM * sizeof(float), stream);
  hipMemsetAsync(cnt, 0, NEXP * sizeof(int), stream);

  k_transpose_cast<<<dim3(HID/32, DIM/32, NEXP), dim3(32, 8), 0, stream>>>(W1, w1t, DIM, HID);
  k_transpose_cast<<<dim3(DIM/32, HID/32, NEXP), dim3(32, 8), 0, stream>>>(W2, w2t, HID, DIM);
  k_router<<<N_TOK/256, 256, 0, stream>>>(x, grad, Wr, br, probs, cnt, tok, wgt);
  if (use_slab) {
    k_moe<1><<<NEXP*MAXT, 256, 0, stream>>>(x, w1t, w2t, b1, b2, cnt, tok, wgt, out, slab);
    k_combine<<<2048, 256, 0, stream>>>(out, slab);
  } else {
    k_moe<0><<<NEXP*MAXT, 256, 0, stream>>>(x, w1t, w2t, b1, b2, cnt, tok, wgt, out, slab);
  }
}

// Round 11
// 218.988 us; speedup vs baseline: 2.1492x; 1.0819x over previous
//
#include <hip/hip_runtime.h>
#include <hip/hip_bf16.h>
#include <cmath>

#define N_TOK 32768
#define DIM   256
#define NEXP  8
#define HID   1024
#define BM    64
#define BH    64
#define MAXT  512   // MAXT*BM == N_TOK: covers worst-case expert load

typedef short bf16x8 __attribute__((ext_vector_type(8)));
typedef float f32x4  __attribute__((ext_vector_type(4)));

__device__ __forceinline__ ushort f2bf(float f) {
  unsigned u = __builtin_bit_cast(unsigned, f);
  u += 0x7fffu + ((u >> 16) & 1u);   // RNE
  return (ushort)(u >> 16);
}

// lh swizzle (128B rows): 16B-slot XOR, max 112 < 128 -> bijective in-row.
__device__ __forceinline__ int lh_slot(int row) {
  return ((row ^ (row >> 3)) & 7) << 4;
}
// lx swizzle (512B rows): (r&7)<<4, max 112 < 512, bijective.
__device__ __forceinline__ int lx_slot(int row) {
  return (row & 7) << 4;
}

// ---------- transpose + cast: src[E][R][C] f32 -> dst[E][C][R] bf16 ----------
__global__ __launch_bounds__(256) void k_transpose_cast(
    const float* __restrict__ src, ushort* __restrict__ dst, int R, int C)
{
  __shared__ float tile[32][33];
  int e = blockIdx.z, rb = blockIdx.y, cb = blockIdx.x;
  int tx = threadIdx.x, ty = threadIdx.y;           // 32 x 8
  const float* s = src + (size_t)e * R * C;
  ushort* d = dst + (size_t)e * R * C;
#pragma unroll
  for (int j = 0; j < 4; ++j)
    tile[ty + 8*j][tx] = s[(size_t)(rb*32 + ty + 8*j) * C + cb*32 + tx];
  __syncthreads();
#pragma unroll
  for (int j = 0; j < 4; ++j)
    d[(size_t)(cb*32 + ty + 8*j) * R + rb*32 + tx] = f2bf(tile[tx][ty + 8*j]);
}

// ---------- router: fp64 logits, softmax, top-2, bucket scatter ----------
// tok entry packs the top-k slot in bit 30: n | (slot<<30).
__global__ __launch_bounds__(256) void k_router(
    const float* __restrict__ x, const float* __restrict__ grad,
    const float* __restrict__ Wr, const float* __restrict__ br,
    float* __restrict__ probs_out,
    int* __restrict__ cnt, int* __restrict__ tok, float* __restrict__ wgt)
{
  __shared__ float xt[256][33];
  __shared__ float wrs[257*8];
  __shared__ float brs[8];
  __shared__ int lcnt[8], lbase[8];
  int tid = threadIdx.x;
  int n = blockIdx.x * 256 + tid;

  for (int i = tid; i < 257*8; i += 256) wrs[i] = Wr[i];
  if (tid < 8) { brs[tid] = br[tid]; lcnt[tid] = 0; }

  double acc[8] = {0,0,0,0,0,0,0,0};
  for (int ch = 0; ch < 8; ++ch) {
    __syncthreads();
    for (int f = tid; f < 2048; f += 256) {
      int r = f >> 3, c0 = (f & 7) * 4;
      float4 v = *(const float4*)(x + (size_t)(blockIdx.x*256 + r)*DIM + ch*32 + c0);
      xt[r][c0] = v.x; xt[r][c0+1] = v.y; xt[r][c0+2] = v.z; xt[r][c0+3] = v.w;
    }
    __syncthreads();
#pragma unroll 4
    for (int c = 0; c < 32; ++c) {
      double xv = (double)xt[tid][c];
      const float* wr = &wrs[(ch*32 + c)*8];
#pragma unroll
      for (int e = 0; e < 8; ++e) acc[e] += xv * (double)wr[e];
    }
  }
  double g = (double)grad[n];
  double lg[8];
#pragma unroll
  for (int e = 0; e < 8; ++e) lg[e] = acc[e] + g*(double)wrs[256*8+e] + (double)brs[e];
  double m = lg[0];
#pragma unroll
  for (int e = 1; e < 8; ++e) m = lg[e] > m ? lg[e] : m;
  double p[8], s = 0.0;
#pragma unroll
  for (int e = 0; e < 8; ++e) { p[e] = exp(lg[e]-m); s += p[e]; }
  double inv = 1.0/s;
#pragma unroll
  for (int e = 0; e < 8; ++e) probs_out[(size_t)n*8 + e] = (float)(p[e]*inv);

  int i0 = 0;
#pragma unroll
  for (int e = 1; e < 8; ++e) if (lg[e] > lg[i0]) i0 = e;
  int i1 = (i0 == 0) ? 1 : 0;
#pragma unroll
  for (int e = 0; e < 8; ++e) if (e != i0 && lg[e] > lg[i1]) i1 = e;
  float w0 = (float)(p[i0]*inv), w1 = (float)(p[i1]*inv);

  int p0 = atomicAdd(&lcnt[i0], 1);
  int p1 = atomicAdd(&lcnt[i1], 1);
  __syncthreads();
  if (tid < 8) lbase[tid] = atomicAdd(&cnt[tid], lcnt[tid]);
  __syncthreads();
  tok[i0*N_TOK + lbase[i0] + p0] = n;              wgt[i0*N_TOK + lbase[i0] + p0] = w0;
  tok[i1*N_TOK + lbase[i1] + p1] = n | (1 << 30);  wgt[i1*N_TOK + lbase[i1] + p1] = w1;
}

// ---------- fused gathered expert MLP ----------
// (256,2): VGPR cap 256/wave; tighter caps spill to scratch (FETCH 530-938 MB).
// e = bid&7: XCD x runs only expert x -> weights L2-resident.
// W1 double-buffered in LDS, staged for c+1 at top of chunk c (drain covered
// by GEMM1+GELU). Slab epilogue: plain stores + k_combine (no atomics).
// r11: GELU via 512-entry piecewise-linear LDS LUT (a + b*v), replacing the
// erf chain (14 instr incl. 2 quarter-rate trans) with 6 VALU + 1 ds_read_b64.
// Interp err <= 1.6e-4 << bf16 rounding of h. VALU-bound diagnosis from r10:
// VALUBusy 42% vs MfmaUtil 15%, ~72% of VALU = GELU+f2bf.
template<int SLAB>
__global__ __launch_bounds__(256, 2) void k_moe(
    const float* __restrict__ x,
    const ushort* __restrict__ w1t,   // [E][H][D] bf16 (transposed)
    const ushort* __restrict__ w2t,   // [E][D][H] bf16 (transposed)
    const float* __restrict__ bias1,  // [E][H]
    const float* __restrict__ bias2,  // [E][D]
    const int* __restrict__ cnt, const int* __restrict__ tok,
    const float* __restrict__ wgt,
    float* __restrict__ out, float* __restrict__ slab)
{
  int e    = blockIdx.x & 7;
  int tile = blockIdx.x >> 3;
  int c = cnt[e];
  int row0 = tile * BM;
  if (row0 >= c) return;
  int rows = min(BM, c - row0);
  int phase = tile & 15;              // stagger concurrent blocks across W chunks

  __shared__ ushort lsA[BM * DIM];    // 32 KB: x tile, then W1 buffer (odd chunks)
  __shared__ ushort lsB[BH * DIM];    // 32 KB: W1 buffer (even chunks)
  __shared__ ushort lh[BM * BH];      // 8 KB h tile
  __shared__ float  lb1[HID];         // 4 KB bias1
  __shared__ float2 lut[512];         // 4 KB gelu LUT: g(v) ~= a + b*v, v in [-8,8]
  // total 80 KB -> 2 blocks/CU

  int tid  = threadIdx.x;
  int lane = tid & 63;
  int wid  = tid >> 6;
  const int l15 = lane & 15;
  const int lk8 = (lane >> 4) * 8;
  const int lr4 = (lane >> 4) * 4;
  const int wr = wid >> 1, wc = wid & 1;   // 2x2 wave grid for GEMM1

  const int*   etok = tok + e * N_TOK + row0;
  const float* ewgt = wgt + e * N_TOK + row0;
  const ushort* W1e = w1t + (size_t)e * HID * DIM;
  const ushort* W2e = w2t + (size_t)e * DIM * HID;

  // ---- prologue: x -> lsA (swizzled), bias1 -> lb1, LUT, W1 chunk0 -> lsB ----
  for (int f = tid; f < BM * (DIM/4); f += 256) {
    int r = f >> 6, c4 = f & 63;
    int t = etok[min(r, rows - 1)] & 0xFFFF;
    float4 v = *(const float4*)(x + (size_t)t * DIM + c4 * 4);
    ushort4 b;
    b.x = f2bf(v.x); b.y = f2bf(v.y); b.z = f2bf(v.z); b.w = f2bf(v.w);
    *(ushort4*)((char*)lsA + r * 512 + ((c4 * 8) ^ lx_slot(r))) = b;
  }
#pragma unroll
  for (int i = 0; i < 4; ++i) lb1[i*256 + tid] = bias1[e*HID + i*256 + tid];
  // gelu LUT: segment i covers [v0, v0+1/32), chord endpoints -> exact at knots
  for (int i = tid; i < 512; i += 256) {
    float v0 = i * 0.03125f - 8.0f;
    float v1 = v0 + 0.03125f;
    float g0 = 0.5f * v0 * (1.0f + erff(v0 * 0.70710678f));
    float g1 = 0.5f * v1 * (1.0f + erff(v1 * 0.70710678f));
    float b  = (g1 - g0) * 32.0f;
    lut[i] = make_float2(g0 - b * v0, b);
  }
  {
    int h0 = (phase & 15) * BH;
#pragma unroll
    for (int i = 0; i < 8; ++i) {
      int u = i*256 + tid;
      int r = u >> 5, s = u & 31;
      const ushort* g = W1e + (size_t)(h0 + r) * DIM + ((s ^ (r & 7)) * 8);
      __builtin_amdgcn_global_load_lds(
          (const __attribute__((address_space(1))) unsigned int*)g,
          (__attribute__((address_space(3))) unsigned int*)(lsB + u*8),
          16, 0, 0);
    }
  }
  __syncthreads();

  // ---- hoist A-fragments to registers once ----
  bf16x8 areg[2][8];
#pragma unroll
  for (int fr = 0; fr < 2; ++fr) {
    int row = wr*32 + fr*16 + l15;
#pragma unroll
    for (int k = 0; k < 8; ++k)
      areg[fr][k] = *(const bf16x8*)((const char*)lsA + row*512
                      + (((k*32 + lk8)*2) ^ lx_slot(row)));
  }
  __syncthreads();   // all waves' areg reads done before lsA is restaged as W1

  f32x4 accY[4][4];
#pragma unroll
  for (int i = 0; i < 4; ++i)
#pragma unroll
    for (int j = 0; j < 4; ++j) accY[i][j] = (f32x4){0.f,0.f,0.f,0.f};

  int sl2[4];
#pragma unroll
  for (int fr = 0; fr < 4; ++fr) sl2[fr] = lh_slot(fr*16 + l15);

  // W1 LDS fragment addressing (ushort units): unit = row*32 + (s ^ (row&7))
  const int b0row = wc*32 + l15;            // b1 row = b0row+16, same (row&7)
  const int bxor  = (b0row & 7);

  for (int cc = 0; cc < HID / BH; ++cc) {
    int chunk = (cc + phase) & 15;
    int h0 = chunk * BH;
    ushort* cur = (cc & 1) ? lsA : lsB;
    ushort* nxt = (cc & 1) ? lsB : lsA;

    // stage W1 for chunk cc+1 FIRST: drain at barrier A covered by GEMM1+GELU
    if (cc < HID/BH - 1) {
      int nh0 = ((cc + 1 + phase) & 15) * BH;
#pragma unroll
      for (int i = 0; i < 8; ++i) {
        int u = i*256 + tid;
        int r = u >> 5, s = u & 31;
        const ushort* g = W1e + (size_t)(nh0 + r) * DIM + ((s ^ (r & 7)) * 8);
        __builtin_amdgcn_global_load_lds(
            (const __attribute__((address_space(1))) unsigned int*)g,
            (__attribute__((address_space(3))) unsigned int*)(nxt + u*8),
            16, 0, 0);
      }
    }

    // W2 B-fragments to regs (consumed after barrier A -> covered)
    bf16x8 bw[2][4];
#pragma unroll
    for (int k2 = 0; k2 < 2; ++k2)
#pragma unroll
      for (int fc = 0; fc < 4; ++fc)
        bw[k2][fc] = *(const bf16x8*)(W2e + (size_t)(wid*64 + fc*16 + l15) * HID
                                      + h0 + k2*32 + lk8);

    f32x4 accH[2][2];
#pragma unroll
    for (int i = 0; i < 2; ++i)
#pragma unroll
      for (int j = 0; j < 2; ++j) accH[i][j] = (f32x4){0.f,0.f,0.f,0.f};

    // GEMM1: h[64x64] = x[64x256] @ W1[256x64]; B from cur (conflict-free)
#pragma unroll
    for (int k = 0; k < 8; ++k) {
      int s = k*4 + (lane >> 4);
      bf16x8 b0 = *(const bf16x8*)(cur + ((b0row     )*32 + (s ^ bxor))*8);
      bf16x8 b1 = *(const bf16x8*)(cur + ((b0row + 16)*32 + (s ^ bxor))*8);
      accH[0][0] = __builtin_amdgcn_mfma_f32_16x16x32_bf16(areg[0][k], b0, accH[0][0], 0, 0, 0);
      accH[1][0] = __builtin_amdgcn_mfma_f32_16x16x32_bf16(areg[1][k], b0, accH[1][0], 0, 0, 0);
      accH[0][1] = __builtin_amdgcn_mfma_f32_16x16x32_bf16(areg[0][k], b1, accH[0][1], 0, 0, 0);
      accH[1][1] = __builtin_amdgcn_mfma_f32_16x16x32_bf16(areg[1][k], b1, accH[1][1], 0, 0, 0);
    }

    // GELU (LUT) + bf16 -> swizzled lh
#pragma unroll
    for (int fc = 0; fc < 2; ++fc) {
      int col = wc*32 + fc*16 + l15;
      float bv = lb1[h0 + col];
#pragma unroll
      for (int fr = 0; fr < 2; ++fr)
#pragma unroll
        for (int j = 0; j < 4; ++j) {
          int row = wr*32 + fr*16 + lr4 + j;
          float v = accH[fr][fc][j] + bv;
          int idx = (int)(v * 32.0f + 256.0f);
          idx = min(max(idx, 0), 511);
          float2 ab = lut[idx];
          float g = fmaf(ab.y, v, ab.x);
          *(ushort*)((char*)lh + row*128 + ((col*2) ^ lh_slot(row))) = f2bf(g);
        }
    }
    __syncthreads();   // barrier A: lh visible; stage + bw drained (covered)

    // GEMM2: y[64x256] += h[64x64] @ W2[64x256]
#pragma unroll
    for (int k2 = 0; k2 < 2; ++k2) {
      bf16x8 a2[4];
#pragma unroll
      for (int fr = 0; fr < 4; ++fr) {
        int row = fr*16 + l15;
        a2[fr] = *(const bf16x8*)((const char*)lh + row*128 + (((k2*32 + lk8)*2) ^ sl2[fr]));
      }
#pragma unroll
      for (int fr = 0; fr < 4; ++fr)
#pragma unroll
        for (int fc = 0; fc < 4; ++fc)
          accY[fr][fc] = __builtin_amdgcn_mfma_f32_16x16x32_bf16(a2[fr], bw[k2][fc], accY[fr][fc], 0, 0, 0);
    }
    __syncthreads();   // barrier B: lh reusable (vm-free -> cheap)
  }

  // epilogue: contribution = w * (y + b2)
  float b2v[4];
#pragma unroll
  for (int fc = 0; fc < 4; ++fc) b2v[fc] = bias2[e*DIM + wid*64 + fc*16 + l15];
#pragma unroll
  for (int fr = 0; fr < 4; ++fr) {
#pragma unroll
    for (int j = 0; j < 4; ++j) {
      int r = fr*16 + lr4 + j;
      if (r < rows) {
        int raw = etok[r];
        int t   = raw & 0xFFFF;
        float w = ewgt[r];
        if (SLAB) {
          // each (token,slot) written by exactly one block -> plain stores
          float* dst = ((raw >> 30) ? slab : out) + (size_t)t * DIM;
#pragma unroll
          for (int fc = 0; fc < 4; ++fc)
            dst[wid*64 + fc*16 + l15] = w * (accY[fr][fc][j] + b2v[fc]);
        } else {
#pragma unroll
          for (int fc = 0; fc < 4; ++fc)
            atomicAdd(out + (size_t)t * DIM + wid*64 + fc*16 + l15,
                      w * (accY[fr][fc][j] + b2v[fc]));
        }
      }
    }
  }
}

// out += slab (slab fully written: every token has exactly one slot-1 entry)
__global__ __launch_bounds__(256) void k_combine(
    float* __restrict__ out, const float* __restrict__ slab)
{
  int stride = gridDim.x * blockDim.x;
  for (int i = blockIdx.x * blockDim.x + threadIdx.x;
       i < N_TOK * DIM / 4; i += stride) {
    float4 a = ((const float4*)out)[i];
    float4 b = ((const float4*)slab)[i];
    a.x += b.x; a.y += b.y; a.z += b.z; a.w += b.w;
    ((float4*)out)[i] = a;
  }
}

extern "C" void kernel_launch(void* const* d_in, const int* in_sizes, int n_in,
                              void* d_out, int out_size, void* d_ws, size_t ws_size,
                              hipStream_t stream)
{
  const float* x    = (const float*)d_in[0];
  const float* grad = (const float*)d_in[1];
  const float* Wr   = (const float*)d_in[2];
  const float* br   = (const float*)d_in[3];
  const float* W1   = (const float*)d_in[4];
  const float* b1   = (const float*)d_in[5];
  const float* W2   = (const float*)d_in[6];
  const float* b2   = (const float*)d_in[7];
  float* out   = (float*)d_out;
  float* probs = out + (size_t)N_TOK * DIM;

  char* wsb = (char*)d_ws;
  int*    cnt = (int*)wsb;                                        // 32 B
  int*    tok = (int*)   (wsb + 4096);                            // 1 MB
  float*  wgt = (float*) (wsb + 4096 + (size_t)NEXP*N_TOK*4);     // 1 MB
  ushort* w1t = (ushort*)(wsb + 4096 + (size_t)NEXP*N_TOK*8);     // 4 MB
  ushort* w2t = w1t + (size_t)NEXP * HID * DIM;                   // 4 MB
  float*  slab = (float*)(wsb + (size_t)(16 << 20));              // 32 MB @ +16MB

  bool use_slab = ws_size >= ((size_t)(16 << 20) + (size_t)N_TOK * DIM * 4);

  hipMemsetAsync(d_out, 0, (size_t)N_TOK * DIM * sizeof(float), stream);
  hipMemsetAsync(cnt, 0, NEXP * sizeof(int), stream);

  k_transpose_cast<<<dim3(HID/32, DIM/32, NEXP), dim3(32, 8), 0, stream>>>(W1, w1t, DIM, HID);
  k_transpose_cast<<<dim3(DIM/32, HID/32, NEXP), dim3(32, 8), 0, stream>>>(W2, w2t, HID, DIM);
  k_router<<<N_TOK/256, 256, 0, stream>>>(x, grad, Wr, br, probs, cnt, tok, wgt);
  if (use_slab) {
    k_moe<1><<<NEXP*MAXT, 256, 0, stream>>>(x, w1t, w2t, b1, b2, cnt, tok, wgt, out, slab);
    k_combine<<<2048, 256, 0, stream>>>(out, slab);
  } else {
    k_moe<0><<<NEXP*MAXT, 256, 0, stream>>>(x, w1t, w2t, b1, b2, cnt, tok, wgt, out, slab);
  }
}